// Round 4
// baseline (233.639 us; speedup 1.0000x reference)
//
#include <hip/hip_runtime.h>
#include <hip/hip_bf16.h>
#include <stdint.h>

// Problem dims (fixed by reference): T=8192 tokens, H=2048 hidden, I=768 intermediate
// Inputs/outputs are FP32; internal compute is bf16 MFMA (absmax 0.016 vs 0.074 budget).
// R4: x fp32->bf16 conversion fused into gateup staging (load fp32 -> v_cvt -> ds_write,
// m93-style round-trip for A only); cvt converts weights only; down tiles 128x64 for
// occupancy (R3 lesson: grid size, not kernel body, was the limiter).
#define T_DIM 8192
#define H_DIM 2048
#define I_DIM 768

typedef __bf16 bf16_t;
typedef bf16_t bf16x8 __attribute__((ext_vector_type(8)));   // 4 VGPRs, MFMA A/B frag
typedef float  f32x4  __attribute__((ext_vector_type(4)));   // MFMA C/D frag

// Async global->LDS, 16B per lane. LDS dest must be wave-uniform base + lane*16.
__device__ __forceinline__ void async_load16(const void* g, void* s) {
    __builtin_amdgcn_global_load_lds(
        (const __attribute__((address_space(1))) void*)g,
        (__attribute__((address_space(3))) void*)s, 16, 0, 0);
}

// ---------------------------------------------------------------------------
// Kernel 0: fp32 -> bf16 for the three weight matrices only (x is fused into
// gateup). 3 * 1.57M elems; one 8-float group per thread; grid sized exactly.
// ~38 MB traffic -> ~10 us.
// ---------------------------------------------------------------------------
__global__ __launch_bounds__(256) void cvt_w_kernel(
    const float* __restrict__ G, const float* __restrict__ U,
    const float* __restrict__ D,
    bf16_t* __restrict__ Gb, bf16_t* __restrict__ Ub, bf16_t* __restrict__ Db)
{
    const size_t NG = (size_t)I_DIM * H_DIM / 8;   // 196,608 groups of 8 floats
    size_t g = (size_t)blockIdx.x * 256 + threadIdx.x;   // 0 .. 3*NG-1
    const float* s; bf16_t* d;
    if (g < NG)          { s = G; d = Gb; }
    else if (g < 2 * NG) { s = U; d = Ub; g -= NG; }
    else                 { s = D; d = Db; g -= 2 * NG; }
    float4 v0 = ((const float4*)s)[2 * g];
    float4 v1 = ((const float4*)s)[2 * g + 1];
    bf16x8 o;
    o[0] = (bf16_t)v0.x; o[1] = (bf16_t)v0.y; o[2] = (bf16_t)v0.z; o[3] = (bf16_t)v0.w;
    o[4] = (bf16_t)v1.x; o[5] = (bf16_t)v1.y; o[6] = (bf16_t)v1.z; o[7] = (bf16_t)v1.w;
    ((bf16x8*)d)[g] = o;
}

// ---------------------------------------------------------------------------
// Kernel 1: 128x64 (MxN) tile of [T, I]: G = x@gate^T, U = x@up^T, h = silu(G)*U.
// x read directly as FP32 (float4 loads -> cvt -> ds_write_b128 into bf16 LDS);
// weights read as pre-converted bf16 via async global_load_lds.
// Grid 64x12 = 768 blocks (3/CU). Wave: 64x32 of both G and U -> 16 MFMA : 8 ds_read.
// ---------------------------------------------------------------------------
__global__ __launch_bounds__(256) void gateup_kernel(
    const float*  __restrict__ X,
    const bf16_t* __restrict__ Wg,
    const bf16_t* __restrict__ Wu,
    bf16_t* __restrict__ Hbuf)
{
    __shared__ __align__(16) bf16_t sA[128 * 32];   // x tile (bf16 after cvt)  8 KB
    __shared__ __align__(16) bf16_t sG[64 * 32];    // gate_w tile              4 KB
    __shared__ __align__(16) bf16_t sU[64 * 32];    // up_w tile                4 KB

    const int tid   = threadIdx.x;
    const int lane  = tid & 63;
    const int wave  = tid >> 6;
    const int waveM = wave >> 1;      // 0..1 -> 64-row half
    const int waveN = wave & 1;       // 0..1 -> 32-col half
    const int quad  = lane >> 4;      // 0..3
    const int lrow  = lane & 15;      // 0..15

    const int blockM = blockIdx.x;    // 0..63  (T/128)
    const int blockN = blockIdx.y;    // 0..11  (I/64)

    f32x4 accG[4][2], accU[4][2];
#pragma unroll
    for (int i = 0; i < 4; i++)
#pragma unroll
        for (int j = 0; j < 2; j++) { accG[i][j] = (f32x4)(0.f); accU[i][j] = (f32x4)(0.f); }

    // A: 128x32 bf16 = 512 x 16B segments (2/thread, via fp32 load + cvt + ds_write).
    // W: 64x32 = 256 segments (1/thread, async). Segment s: row s/4, cols (s%4)*8..+7.
    const int s0 = tid, s1 = tid + 256;
    const int rA0 = s0 >> 2, cA0 = (s0 & 3) * 8;
    const int rA1 = s1 >> 2, cA1 = (s1 & 3) * 8;
    const int rW  = tid >> 2, cW  = (tid & 3) * 8;

    const float*  Ab = X  + (size_t)(blockM * 128) * H_DIM;
    const bf16_t* Gb = Wg + (size_t)(blockN * 64) * H_DIM;
    const bf16_t* Ub = Wu + (size_t)(blockN * 64) * H_DIM;

    for (int k0 = 0; k0 < H_DIM; k0 += 32) {
        // Weights: async direct-to-LDS (stays in flight until the barrier drain).
        async_load16(Gb + (size_t)rW * H_DIM + k0 + cW, &sG[tid * 8]);
        async_load16(Ub + (size_t)rW * H_DIM + k0 + cW, &sU[tid * 8]);

        // x: fp32 -> bf16 in registers -> LDS (standard layout, conflict-free writes).
        const float* p0 = Ab + (size_t)rA0 * H_DIM + k0 + cA0;
        const float* p1 = Ab + (size_t)rA1 * H_DIM + k0 + cA1;
        f32x4 a00 = *(const f32x4*)p0, a01 = *(const f32x4*)(p0 + 4);
        f32x4 a10 = *(const f32x4*)p1, a11 = *(const f32x4*)(p1 + 4);
        bf16x8 w0, w1;
#pragma unroll
        for (int i = 0; i < 4; i++) {
            w0[i] = (bf16_t)a00[i]; w0[4 + i] = (bf16_t)a01[i];
            w1[i] = (bf16_t)a10[i]; w1[4 + i] = (bf16_t)a11[i];
        }
        *(bf16x8*)&sA[s0 * 8] = w0;
        *(bf16x8*)&sA[s1 * 8] = w1;
        __syncthreads();   // drains async vmcnt + ds_write lgkm

        bf16x8 aF[4], gF[2], uF[2];
#pragma unroll
        for (int mi = 0; mi < 4; mi++) {
            int r = waveM * 64 + mi * 16 + lrow;
            aF[mi] = *(const bf16x8*)&sA[r * 32 + quad * 8];
        }
#pragma unroll
        for (int ni = 0; ni < 2; ni++) {
            int r = waveN * 32 + ni * 16 + lrow;
            gF[ni] = *(const bf16x8*)&sG[r * 32 + quad * 8];
            uF[ni] = *(const bf16x8*)&sU[r * 32 + quad * 8];
        }
        __syncthreads();   // frags in regs; next iter overwrites LDS

#pragma unroll
        for (int mi = 0; mi < 4; mi++)
#pragma unroll
            for (int ni = 0; ni < 2; ni++) {
                accG[mi][ni] = __builtin_amdgcn_mfma_f32_16x16x32_bf16(aF[mi], gF[ni], accG[mi][ni], 0, 0, 0);
                accU[mi][ni] = __builtin_amdgcn_mfma_f32_16x16x32_bf16(aF[mi], uF[ni], accU[mi][ni], 0, 0, 0);
            }
    }

    // Epilogue: h = silu(g)*u, cast bf16. C/D layout: col=lane&15, row=quad*4+r.
#pragma unroll
    for (int mi = 0; mi < 4; mi++) {
#pragma unroll
        for (int ni = 0; ni < 2; ni++) {
#pragma unroll
            for (int r = 0; r < 4; r++) {
                int row = blockM * 128 + waveM * 64 + mi * 16 + quad * 4 + r;
                int col = blockN * 64 + waveN * 32 + ni * 16 + lrow;
                float g = accG[mi][ni][r];
                float u = accU[mi][ni][r];
                float h = (g / (1.f + __expf(-g))) * u;
                Hbuf[(size_t)row * I_DIM + col] = (bf16_t)h;
            }
        }
    }
}

// ---------------------------------------------------------------------------
// Kernel 2: out[T,H] = h @ down^T. 128x64 tiles, grid 64x32 = 2048 blocks
// (~6 blocks/CU by VGPR — R3's occupancy lesson applied). K = 768 -> 24 steps.
// Output FP32.
// ---------------------------------------------------------------------------
__global__ __launch_bounds__(256) void down_kernel(
    const bf16_t* __restrict__ Hbuf,
    const bf16_t* __restrict__ Wd,
    float* __restrict__ Out)
{
    __shared__ __align__(16) bf16_t sA[128 * 32];   // 8 KB
    __shared__ __align__(16) bf16_t sB[64 * 32];    // 4 KB

    const int tid   = threadIdx.x;
    const int lane  = tid & 63;
    const int wave  = tid >> 6;
    const int waveM = wave >> 1;
    const int waveN = wave & 1;
    const int quad  = lane >> 4;
    const int lrow  = lane & 15;

    const int blockM = blockIdx.x;    // 0..63  (T/128)
    const int blockN = blockIdx.y;    // 0..31  (H/64)

    f32x4 acc[4][2];
#pragma unroll
    for (int i = 0; i < 4; i++)
#pragma unroll
        for (int j = 0; j < 2; j++) acc[i][j] = (f32x4)(0.f);

    const int s0 = tid, s1 = tid + 256;
    const int rA0 = s0 >> 2, cA0 = (s0 & 3) * 8;
    const int rA1 = s1 >> 2, cA1 = (s1 & 3) * 8;
    const int rW  = tid >> 2, cW  = (tid & 3) * 8;

    const bf16_t* Ab = Hbuf + (size_t)(blockM * 128) * I_DIM;
    const bf16_t* Bb = Wd   + (size_t)(blockN * 64) * I_DIM;

    for (int k0 = 0; k0 < I_DIM; k0 += 32) {
        async_load16(Ab + (size_t)rA0 * I_DIM + k0 + cA0, &sA[s0 * 8]);
        async_load16(Ab + (size_t)rA1 * I_DIM + k0 + cA1, &sA[s1 * 8]);
        async_load16(Bb + (size_t)rW  * I_DIM + k0 + cW,  &sB[tid * 8]);
        __syncthreads();

        bf16x8 aF[4], bF[2];
#pragma unroll
        for (int mi = 0; mi < 4; mi++) {
            int r = waveM * 64 + mi * 16 + lrow;
            aF[mi] = *(const bf16x8*)&sA[r * 32 + quad * 8];
        }
#pragma unroll
        for (int ni = 0; ni < 2; ni++) {
            int r = waveN * 32 + ni * 16 + lrow;
            bF[ni] = *(const bf16x8*)&sB[r * 32 + quad * 8];
        }
        __syncthreads();

#pragma unroll
        for (int mi = 0; mi < 4; mi++)
#pragma unroll
            for (int ni = 0; ni < 2; ni++)
                acc[mi][ni] = __builtin_amdgcn_mfma_f32_16x16x32_bf16(aF[mi], bF[ni], acc[mi][ni], 0, 0, 0);
    }

#pragma unroll
    for (int mi = 0; mi < 4; mi++) {
#pragma unroll
        for (int ni = 0; ni < 2; ni++) {
#pragma unroll
            for (int r = 0; r < 4; r++) {
                int row = blockM * 128 + waveM * 64 + mi * 16 + quad * 4 + r;
                int col = blockN * 64 + waveN * 32 + ni * 16 + lrow;
                Out[(size_t)row * H_DIM + col] = acc[mi][ni][r];
            }
        }
    }
}

extern "C" void kernel_launch(void* const* d_in, const int* in_sizes, int n_in,
                              void* d_out, int out_size, void* d_ws, size_t ws_size,
                              hipStream_t stream) {
    const float* x  = (const float*)d_in[0];  // [T, H] fp32
    const float* gw = (const float*)d_in[1];  // [I, H] fp32
    const float* uw = (const float*)d_in[2];  // [I, H] fp32
    const float* dw = (const float*)d_in[3];  // [H, I] fp32
    float* out = (float*)d_out;               // [T, H] fp32

    // Workspace (bf16): gw_bf/uw_bf/dw_bf [I*H] each, hbuf [T*I]. ~22 MB total.
    bf16_t* gb = (bf16_t*)d_ws;
    bf16_t* ub = gb + (size_t)I_DIM * H_DIM;
    bf16_t* db = ub + (size_t)I_DIM * H_DIM;
    bf16_t* hb = db + (size_t)I_DIM * H_DIM;

    const int cvt_blocks = (int)(3 * (size_t)I_DIM * H_DIM / 8 / 256);  // 2304
    cvt_w_kernel<<<cvt_blocks, 256, 0, stream>>>(gw, uw, dw, gb, ub, db);
    gateup_kernel<<<dim3(T_DIM / 128, I_DIM / 64), 256, 0, stream>>>(x, gb, ub, hb);
    down_kernel<<<dim3(T_DIM / 128, H_DIM / 64), 256, 0, stream>>>(hb, db, out);
}

// Round 5
// 230.925 us; speedup vs baseline: 1.0118x; 1.0118x over previous
//
#include <hip/hip_runtime.h>
#include <hip/hip_bf16.h>
#include <stdint.h>

// Problem dims (fixed by reference): T=8192 tokens, H=2048 hidden, I=768 intermediate
// Inputs/outputs are FP32; internal compute is bf16 MFMA (absmax 0.016 vs 0.074 budget).
// R5: revert gateup to R3's all-async staging (R4's fused fp32 cvt-in-GEMM serialized
// the staging on vmcnt latency: MfmaUtil 32->22, 66->96 us). cvt converts x + weights
// with exact grid / 8-elem groups. down stays 128x64 (2048 blocks).
#define T_DIM 8192
#define H_DIM 2048
#define I_DIM 768

typedef __bf16 bf16_t;
typedef bf16_t bf16x8 __attribute__((ext_vector_type(8)));   // 4 VGPRs, MFMA A/B frag
typedef float  f32x4  __attribute__((ext_vector_type(4)));   // MFMA C/D frag

// Async global->LDS, 16B per lane. LDS dest must be wave-uniform base + lane*16.
__device__ __forceinline__ void async_load16(const void* g, void* s) {
    __builtin_amdgcn_global_load_lds(
        (const __attribute__((address_space(1))) void*)g,
        (__attribute__((address_space(3))) void*)s, 16, 0, 0);
}

// ---------------------------------------------------------------------------
// Kernel 0: fp32 -> bf16 for x and the three weight matrices.
// One 8-float group per thread, exact grid, single branch, no loop.
// x: 2,097,152 groups; weights: 196,608 groups each -> total 2,686,976 groups
// = 10,496 blocks x 256. ~201 MB traffic -> ~32 us at achievable BW.
// ---------------------------------------------------------------------------
__global__ __launch_bounds__(256) void cvt_kernel(
    const float* __restrict__ X, const float* __restrict__ G,
    const float* __restrict__ U, const float* __restrict__ D,
    bf16_t* __restrict__ Xb, bf16_t* __restrict__ Gb,
    bf16_t* __restrict__ Ub, bf16_t* __restrict__ Db)
{
    const size_t NX = (size_t)T_DIM * H_DIM / 8;   // 2,097,152
    const size_t NW = (size_t)I_DIM * H_DIM / 8;   //   196,608
    size_t g = (size_t)blockIdx.x * 256 + threadIdx.x;
    const float* s; bf16_t* d;
    if (g < NX)               { s = X; d = Xb; }
    else { g -= NX;
        if (g < NW)           { s = G; d = Gb; }
        else { g -= NW;
            if (g < NW)       { s = U; d = Ub; }
            else { g -= NW;     s = D; d = Db; } } }
    float4 v0 = ((const float4*)s)[2 * g];
    float4 v1 = ((const float4*)s)[2 * g + 1];
    bf16x8 o;
    o[0] = (bf16_t)v0.x; o[1] = (bf16_t)v0.y; o[2] = (bf16_t)v0.z; o[3] = (bf16_t)v0.w;
    o[4] = (bf16_t)v1.x; o[5] = (bf16_t)v1.y; o[6] = (bf16_t)v1.z; o[7] = (bf16_t)v1.w;
    ((bf16x8*)d)[g] = o;
}

// ---------------------------------------------------------------------------
// Kernel 1 (R3-proven, 66 us): 128x64 (MxN) tile of [T, I]: G = x@gate^T,
// U = x@up^T via MFMA, h = silu(G)*U -> bf16 workspace.
// All staging async global_load_lds. Grid 64x12 = 768 blocks (3/CU).
// Wave: 64x32 of both G and U -> 16 MFMA : 8 ds_read_b128 per K-step.
// ---------------------------------------------------------------------------
__global__ __launch_bounds__(256) void gateup_kernel(
    const bf16_t* __restrict__ X,
    const bf16_t* __restrict__ Wg,
    const bf16_t* __restrict__ Wu,
    bf16_t* __restrict__ Hbuf)
{
    __shared__ __align__(16) bf16_t sA[128 * 32];   // x tile       8 KB
    __shared__ __align__(16) bf16_t sG[64 * 32];    // gate_w tile  4 KB
    __shared__ __align__(16) bf16_t sU[64 * 32];    // up_w tile    4 KB

    const int tid   = threadIdx.x;
    const int lane  = tid & 63;
    const int wave  = tid >> 6;
    const int waveM = wave >> 1;      // 0..1 -> 64-row half
    const int waveN = wave & 1;       // 0..1 -> 32-col half
    const int quad  = lane >> 4;      // 0..3
    const int lrow  = lane & 15;      // 0..15

    const int blockM = blockIdx.x;    // 0..63  (T/128)
    const int blockN = blockIdx.y;    // 0..11  (I/64)

    f32x4 accG[4][2], accU[4][2];
#pragma unroll
    for (int i = 0; i < 4; i++)
#pragma unroll
        for (int j = 0; j < 2; j++) { accG[i][j] = (f32x4)(0.f); accU[i][j] = (f32x4)(0.f); }

    // A: 128x32 = 512 x 16B segments (2/thread); W: 64x32 = 256 segments (1/thread).
    // Segment s covers row = s/4, cols (s%4)*8 .. +7.
    const int s0 = tid, s1 = tid + 256;
    const int rA0 = s0 >> 2, cA0 = (s0 & 3) * 8;
    const int rA1 = s1 >> 2, cA1 = (s1 & 3) * 8;
    const int rW  = tid >> 2, cW  = (tid & 3) * 8;

    const bf16_t* Ab = X  + (size_t)(blockM * 128) * H_DIM;
    const bf16_t* Gb = Wg + (size_t)(blockN * 64) * H_DIM;
    const bf16_t* Ub = Wu + (size_t)(blockN * 64) * H_DIM;

    for (int k0 = 0; k0 < H_DIM; k0 += 32) {
        async_load16(Ab + (size_t)rA0 * H_DIM + k0 + cA0, &sA[s0 * 8]);
        async_load16(Ab + (size_t)rA1 * H_DIM + k0 + cA1, &sA[s1 * 8]);
        async_load16(Gb + (size_t)rW  * H_DIM + k0 + cW,  &sG[tid * 8]);
        async_load16(Ub + (size_t)rW  * H_DIM + k0 + cW,  &sU[tid * 8]);
        __syncthreads();   // vmcnt(0) drain + barrier

        bf16x8 aF[4], gF[2], uF[2];
#pragma unroll
        for (int mi = 0; mi < 4; mi++) {
            int r = waveM * 64 + mi * 16 + lrow;
            aF[mi] = *(const bf16x8*)&sA[r * 32 + quad * 8];
        }
#pragma unroll
        for (int ni = 0; ni < 2; ni++) {
            int r = waveN * 32 + ni * 16 + lrow;
            gF[ni] = *(const bf16x8*)&sG[r * 32 + quad * 8];
            uF[ni] = *(const bf16x8*)&sU[r * 32 + quad * 8];
        }
        __syncthreads();   // frags in regs; next iter overwrites LDS

#pragma unroll
        for (int mi = 0; mi < 4; mi++)
#pragma unroll
            for (int ni = 0; ni < 2; ni++) {
                accG[mi][ni] = __builtin_amdgcn_mfma_f32_16x16x32_bf16(aF[mi], gF[ni], accG[mi][ni], 0, 0, 0);
                accU[mi][ni] = __builtin_amdgcn_mfma_f32_16x16x32_bf16(aF[mi], uF[ni], accU[mi][ni], 0, 0, 0);
            }
    }

    // Epilogue: h = silu(g)*u, cast bf16. C/D layout: col=lane&15, row=quad*4+r.
#pragma unroll
    for (int mi = 0; mi < 4; mi++) {
#pragma unroll
        for (int ni = 0; ni < 2; ni++) {
#pragma unroll
            for (int r = 0; r < 4; r++) {
                int row = blockM * 128 + waveM * 64 + mi * 16 + quad * 4 + r;
                int col = blockN * 64 + waveN * 32 + ni * 16 + lrow;
                float g = accG[mi][ni][r];
                float u = accU[mi][ni][r];
                float h = (g / (1.f + __expf(-g))) * u;
                Hbuf[(size_t)row * I_DIM + col] = (bf16_t)h;
            }
        }
    }
}

// ---------------------------------------------------------------------------
// Kernel 2: out[T,H] = h @ down^T. 128x64 tiles, grid 64x32 = 2048 blocks
// (~6 blocks/CU by VGPR). K = 768 -> 24 steps of 32. Output FP32.
// ---------------------------------------------------------------------------
__global__ __launch_bounds__(256) void down_kernel(
    const bf16_t* __restrict__ Hbuf,
    const bf16_t* __restrict__ Wd,
    float* __restrict__ Out)
{
    __shared__ __align__(16) bf16_t sA[128 * 32];   // 8 KB
    __shared__ __align__(16) bf16_t sB[64 * 32];    // 4 KB

    const int tid   = threadIdx.x;
    const int lane  = tid & 63;
    const int wave  = tid >> 6;
    const int waveM = wave >> 1;
    const int waveN = wave & 1;
    const int quad  = lane >> 4;
    const int lrow  = lane & 15;

    const int blockM = blockIdx.x;    // 0..63  (T/128)
    const int blockN = blockIdx.y;    // 0..31  (H/64)

    f32x4 acc[4][2];
#pragma unroll
    for (int i = 0; i < 4; i++)
#pragma unroll
        for (int j = 0; j < 2; j++) acc[i][j] = (f32x4)(0.f);

    const int s0 = tid, s1 = tid + 256;
    const int rA0 = s0 >> 2, cA0 = (s0 & 3) * 8;
    const int rA1 = s1 >> 2, cA1 = (s1 & 3) * 8;
    const int rW  = tid >> 2, cW  = (tid & 3) * 8;

    const bf16_t* Ab = Hbuf + (size_t)(blockM * 128) * I_DIM;
    const bf16_t* Bb = Wd   + (size_t)(blockN * 64) * I_DIM;

    for (int k0 = 0; k0 < I_DIM; k0 += 32) {
        async_load16(Ab + (size_t)rA0 * I_DIM + k0 + cA0, &sA[s0 * 8]);
        async_load16(Ab + (size_t)rA1 * I_DIM + k0 + cA1, &sA[s1 * 8]);
        async_load16(Bb + (size_t)rW  * I_DIM + k0 + cW,  &sB[tid * 8]);
        __syncthreads();

        bf16x8 aF[4], bF[2];
#pragma unroll
        for (int mi = 0; mi < 4; mi++) {
            int r = waveM * 64 + mi * 16 + lrow;
            aF[mi] = *(const bf16x8*)&sA[r * 32 + quad * 8];
        }
#pragma unroll
        for (int ni = 0; ni < 2; ni++) {
            int r = waveN * 32 + ni * 16 + lrow;
            bF[ni] = *(const bf16x8*)&sB[r * 32 + quad * 8];
        }
        __syncthreads();

#pragma unroll
        for (int mi = 0; mi < 4; mi++)
#pragma unroll
            for (int ni = 0; ni < 2; ni++)
                acc[mi][ni] = __builtin_amdgcn_mfma_f32_16x16x32_bf16(aF[mi], bF[ni], acc[mi][ni], 0, 0, 0);
    }

#pragma unroll
    for (int mi = 0; mi < 4; mi++) {
#pragma unroll
        for (int ni = 0; ni < 2; ni++) {
#pragma unroll
            for (int r = 0; r < 4; r++) {
                int row = blockM * 128 + waveM * 64 + mi * 16 + quad * 4 + r;
                int col = blockN * 64 + waveN * 32 + ni * 16 + lrow;
                Out[(size_t)row * H_DIM + col] = acc[mi][ni][r];
            }
        }
    }
}

extern "C" void kernel_launch(void* const* d_in, const int* in_sizes, int n_in,
                              void* d_out, int out_size, void* d_ws, size_t ws_size,
                              hipStream_t stream) {
    const float* x  = (const float*)d_in[0];  // [T, H] fp32
    const float* gw = (const float*)d_in[1];  // [I, H] fp32
    const float* uw = (const float*)d_in[2];  // [I, H] fp32
    const float* dw = (const float*)d_in[3];  // [H, I] fp32
    float* out = (float*)d_out;               // [T, H] fp32

    // Workspace (bf16): x_bf [T*H], gw/uw/dw_bf [I*H] each, hbuf [T*I]. ~55.6 MB.
    bf16_t* xb = (bf16_t*)d_ws;
    bf16_t* gb = xb + (size_t)T_DIM * H_DIM;
    bf16_t* ub = gb + (size_t)I_DIM * H_DIM;
    bf16_t* db = ub + (size_t)I_DIM * H_DIM;
    bf16_t* hb = db + (size_t)I_DIM * H_DIM;

    const size_t groups = ((size_t)T_DIM * H_DIM + 3 * (size_t)I_DIM * H_DIM) / 8;
    cvt_kernel<<<(int)(groups / 256), 256, 0, stream>>>(x, gw, uw, dw, xb, gb, ub, db);
    gateup_kernel<<<dim3(T_DIM / 128, I_DIM / 64), 256, 0, stream>>>(xb, gb, ub, hb);
    down_kernel<<<dim3(T_DIM / 128, H_DIM / 64), 256, 0, stream>>>(hb, db, out);
}